// Round 6
// baseline (173.360 us; speedup 1.0000x reference)
//
#include <hip/hip_runtime.h>
#include <math.h>

static constexpr int B_ = 32;
static constexpr int T_ = 512;
static constexpr int H_ = 768;
static constexpr int NL = 12;                 // layers 1..12 of 13
static constexpr int CHUNKS = 128;            // blocks per batch item
static constexpr int TOK_PER_BLK = T_ / CHUNKS;   // 4
static constexpr int THREADS = H_ / 4;        // 192 (3 waves)
static constexpr int NW = THREADS / 64;       // 3

typedef float f4 __attribute__((ext_vector_type(4)));

// Order-preserving float -> uint encoding so unsigned atomicMax == float max.
// Every finite/inf float encodes > 0x00000000, so memset(0) is the identity.
__device__ __forceinline__ unsigned fenc(float f) {
  unsigned u = __float_as_uint(f);
  return (u & 0x80000000u) ? ~u : (u | 0x80000000u);
}
__device__ __forceinline__ float fdec(unsigned e) {
  return __uint_as_float((e & 0x80000000u) ? (e ^ 0x80000000u) : ~e);
}

// Full wave64 sum via DPP (VALU only, no LDS pipe). Valid in lane 63.
__device__ __forceinline__ float wave64_sum(float x) {
#define DPPADD(ctrl)                                                          \
  x += __int_as_float(__builtin_amdgcn_update_dpp(                            \
      0, __float_as_int(x), (ctrl), 0xf, 0xf, true))
  DPPADD(0x111);  // row_shr:1
  DPPADD(0x112);  // row_shr:2
  DPPADD(0x114);  // row_shr:4
  DPPADD(0x118);  // row_shr:8  -> lanes 15/31/47/63 hold row sums
  DPPADD(0x142);  // row_bcast:15 -> lane31: rows0+1, lane63: rows2+3
  DPPADD(0x143);  // row_bcast:31 -> lane63: full wave sum
#undef DPPADD
  return x;
}

__global__ __launch_bounds__(THREADS) void bissect_pool(
    const float* __restrict__ hs, const float* __restrict__ mask,
    unsigned* __restrict__ pooled) {
  const int tid = threadIdx.x;
  const int b = blockIdx.x / CHUNKS;
  const int chunk = blockIdx.x % CHUNKS;
  const int wave = tid >> 6;
  const int lane = tid & 63;
  // Double-buffered cross-wave reduce. Buffer rb is re-written 2 tokens
  // later with an intervening barrier -> race-free.
  __shared__ float red[2][NW][NL];

  const size_t layer_stride = (size_t)B_ * T_ * H_;
  const float* tok0 = hs + layer_stride +
                      ((size_t)b * T_ + (size_t)(chunk * TOK_PER_BLK)) * H_ + 4 * tid;
  const float* mrow = mask + (size_t)b * T_ + (size_t)(chunk * TOK_PER_BLK);

  f4 pmax = {-INFINITY, -INFINITY, -INFINITY, -INFINITY};
  f4 dA[NL], dB[NL];

  // Issue token ti's 12 float4 nontemporal loads (read-once data).
#define LOADT(buf, ti)                                                        \
  do {                                                                        \
    const float* _p = tok0 + (size_t)(ti) * H_;                               \
    _Pragma("unroll")                                                         \
    for (int n = 0; n < NL; ++n)                                              \
      buf[n] = __builtin_nontemporal_load(                                    \
          reinterpret_cast<const f4*>(_p + (size_t)n * layer_stride));        \
  } while (0)

#define PROCT(buf, ti, rb)                                                    \
  do {                                                                        \
    f4 v = buf[0];                                                            \
    _Pragma("unroll")                                                         \
    for (int n = 1; n < NL; ++n) v += buf[n];                                 \
    v *= (1.0f / 12.0f);                                                      \
    float s[NL];                                                              \
    _Pragma("unroll")                                                         \
    for (int n = 0; n < NL; ++n)                                              \
      s[n] = v.x * buf[n].x + v.y * buf[n].y + v.z * buf[n].z + v.w * buf[n].w;\
    _Pragma("unroll")                                                         \
    for (int n = 0; n < NL; ++n) s[n] = wave64_sum(s[n]);                     \
    if (lane == 63) {                                                         \
      _Pragma("unroll")                                                       \
      for (int n = 0; n < NL; ++n) red[rb][wave][n] = s[n];                   \
    }                                                                         \
    __syncthreads();                                                          \
    _Pragma("unroll")                                                         \
    for (int n = 0; n < NL; ++n)                                              \
      s[n] = red[rb][0][n] + red[rb][1][n] + red[rb][2][n];                   \
    float m = s[0];                                                           \
    _Pragma("unroll")                                                         \
    for (int n = 1; n < NL; ++n) m = fmaxf(m, s[n]);                          \
    float e[NL], esum = 0.f;                                                  \
    _Pragma("unroll")                                                         \
    for (int n = 0; n < NL; ++n) { e[n] = __expf(s[n] - m); esum += e[n]; }   \
    const float scale = mrow[ti] / esum;                                      \
    f4 fin = {0.f, 0.f, 0.f, 0.f};                                            \
    _Pragma("unroll")                                                         \
    for (int n = 0; n < NL; ++n) fin += buf[n] * e[n];                        \
    fin *= scale;                                                             \
    pmax.x = fmaxf(pmax.x, fin.x);                                            \
    pmax.y = fmaxf(pmax.y, fin.y);                                            \
    pmax.z = fmaxf(pmax.z, fin.z);                                            \
    pmax.w = fmaxf(pmax.w, fin.w);                                            \
  } while (0)

  // 2-deep load pipeline; unroll 1 keeps exactly two bodies in scheduling
  // scope (R2's full unroll caused spill catastrophe).
  LOADT(dA, 0);
#pragma unroll 1
  for (int i = 0; i + 2 < TOK_PER_BLK; i += 2) {
    LOADT(dB, i + 1);
    PROCT(dA, i, 0);
    LOADT(dA, i + 2);
    PROCT(dB, i + 1, 1);
  }
  LOADT(dB, TOK_PER_BLK - 1);
  PROCT(dA, TOK_PER_BLK - 2, 0);
  PROCT(dB, TOK_PER_BLK - 1, 1);
#undef LOADT
#undef PROCT

  unsigned* pp = pooled + (size_t)b * H_ + 4 * tid;
  atomicMax(pp + 0, fenc(pmax.x));
  atomicMax(pp + 1, fenc(pmax.y));
  atomicMax(pp + 2, fenc(pmax.z));
  atomicMax(pp + 3, fenc(pmax.w));
}

__global__ __launch_bounds__(256) void logits_kernel(
    const unsigned* __restrict__ pooled, const float* __restrict__ W,
    const float* __restrict__ bias, float* __restrict__ out) {
  const int b = blockIdx.x;
  const int tid = threadIdx.x;
  float a0 = 0.f, a1 = 0.f;
  for (int h = tid; h < H_; h += 256) {
    const float p = fdec(pooled[(size_t)b * H_ + h]);
    a0 += p * W[h];
    a1 += p * W[H_ + h];
  }
#pragma unroll
  for (int off = 32; off >= 1; off >>= 1) {
    a0 += __shfl_xor(a0, off);
    a1 += __shfl_xor(a1, off);
  }
  __shared__ float r0[4], r1[4];
  const int wave = tid >> 6, lane = tid & 63;
  if (lane == 0) { r0[wave] = a0; r1[wave] = a1; }
  __syncthreads();
  if (tid == 0) {
    out[b * 2 + 0] = r0[0] + r0[1] + r0[2] + r0[3] + bias[0];
    out[b * 2 + 1] = r1[0] + r1[1] + r1[2] + r1[3] + bias[1];
  }
}

extern "C" void kernel_launch(void* const* d_in, const int* in_sizes, int n_in,
                              void* d_out, int out_size, void* d_ws, size_t ws_size,
                              hipStream_t stream) {
  const float* hs   = (const float*)d_in[0];
  const float* mask = (const float*)d_in[1];
  const float* W    = (const float*)d_in[2];
  const float* bias = (const float*)d_in[3];
  float* out = (float*)d_out;
  unsigned* pooled = (unsigned*)d_ws;  // B_*H_ u32 = 96 KiB

  hipMemsetAsync(pooled, 0, (size_t)B_ * H_ * sizeof(unsigned), stream);
  hipLaunchKernelGGL(bissect_pool, dim3(B_ * CHUNKS), dim3(THREADS), 0, stream,
                     hs, mask, pooled);
  hipLaunchKernelGGL(logits_kernel, dim3(B_), dim3(256), 0, stream,
                     pooled, W, bias, out);
}

// Round 7
// 106.949 us; speedup vs baseline: 1.6210x; 1.6210x over previous
//
#include <hip/hip_runtime.h>
#include <math.h>

static constexpr int B_ = 32;
static constexpr int T_ = 512;
static constexpr int H_ = 768;
static constexpr int NL = 12;                 // layers 1..12 of 13
static constexpr int CHUNKS = 32;             // blocks per batch item
static constexpr int TOK_PER_BLK = T_ / CHUNKS;   // 16
static constexpr int THREADS = H_ / 4;        // 192 (3 waves)
static constexpr int NW = THREADS / 64;       // 3

typedef float f4 __attribute__((ext_vector_type(4)));

// Order-preserving float -> uint encoding so unsigned atomicMax == float max.
// Every finite/inf float encodes > 0x00000000, so memset(0) is the identity.
__device__ __forceinline__ unsigned fenc(float f) {
  unsigned u = __float_as_uint(f);
  return (u & 0x80000000u) ? ~u : (u | 0x80000000u);
}
__device__ __forceinline__ float fdec(unsigned e) {
  return __uint_as_float((e & 0x80000000u) ? (e ^ 0x80000000u) : ~e);
}

// Full wave64 sum via DPP (VALU only, no LDS pipe). Valid in lane 63.
__device__ __forceinline__ float wave64_sum(float x) {
#define DPPADD(ctrl)                                                          \
  x += __int_as_float(__builtin_amdgcn_update_dpp(                            \
      0, __float_as_int(x), (ctrl), 0xf, 0xf, true))
  DPPADD(0x111);  // row_shr:1
  DPPADD(0x112);  // row_shr:2
  DPPADD(0x114);  // row_shr:4
  DPPADD(0x118);  // row_shr:8  -> lanes 15/31/47/63 hold row sums
  DPPADD(0x142);  // row_bcast:15 -> lane31: rows0+1, lane63: rows2+3
  DPPADD(0x143);  // row_bcast:31 -> lane63: full wave sum
#undef DPPADD
  return x;
}

__global__ __launch_bounds__(THREADS) void bissect_pool(
    const float* __restrict__ hs, const float* __restrict__ mask,
    unsigned* __restrict__ pooled) {
  const int tid = threadIdx.x;
  const int b = blockIdx.x / CHUNKS;
  const int chunk = blockIdx.x % CHUNKS;
  const int wave = tid >> 6;
  const int lane = tid & 63;
  // Double-buffered cross-wave reduce. Buffer rb is re-written 2 tokens
  // later with an intervening barrier -> race-free.
  __shared__ float red[2][NW][NL];

  const size_t layer_stride = (size_t)B_ * T_ * H_;
  const float* tok0 = hs + layer_stride +
                      ((size_t)b * T_ + (size_t)(chunk * TOK_PER_BLK)) * H_ + 4 * tid;
  const float* mrow = mask + (size_t)b * T_ + (size_t)(chunk * TOK_PER_BLK);

  f4 pmax = {-INFINITY, -INFINITY, -INFINITY, -INFINITY};
  f4 dA[NL], dB[NL];

  // Issue token ti's 12 float4 nontemporal loads (read-once data).
#define LOADT(buf, ti)                                                        \
  do {                                                                        \
    const float* _p = tok0 + (size_t)(ti) * H_;                               \
    _Pragma("unroll")                                                         \
    for (int n = 0; n < NL; ++n)                                              \
      buf[n] = __builtin_nontemporal_load(                                    \
          reinterpret_cast<const f4*>(_p + (size_t)n * layer_stride));        \
  } while (0)

#define PROCT(buf, ti, rb)                                                    \
  do {                                                                        \
    f4 v = buf[0];                                                            \
    _Pragma("unroll")                                                         \
    for (int n = 1; n < NL; ++n) v += buf[n];                                 \
    v *= (1.0f / 12.0f);                                                      \
    float s[NL];                                                              \
    _Pragma("unroll")                                                         \
    for (int n = 0; n < NL; ++n)                                              \
      s[n] = v.x * buf[n].x + v.y * buf[n].y + v.z * buf[n].z + v.w * buf[n].w;\
    _Pragma("unroll")                                                         \
    for (int n = 0; n < NL; ++n) s[n] = wave64_sum(s[n]);                     \
    if (lane == 63) {                                                         \
      _Pragma("unroll")                                                       \
      for (int n = 0; n < NL; ++n) red[rb][wave][n] = s[n];                   \
    }                                                                         \
    __syncthreads();                                                          \
    _Pragma("unroll")                                                         \
    for (int n = 0; n < NL; ++n)                                              \
      s[n] = red[rb][0][n] + red[rb][1][n] + red[rb][2][n];                   \
    float m = s[0];                                                           \
    _Pragma("unroll")                                                         \
    for (int n = 1; n < NL; ++n) m = fmaxf(m, s[n]);                          \
    float e[NL], esum = 0.f;                                                  \
    _Pragma("unroll")                                                         \
    for (int n = 0; n < NL; ++n) { e[n] = __expf(s[n] - m); esum += e[n]; }   \
    const float scale = mrow[ti] / esum;                                      \
    f4 fin = {0.f, 0.f, 0.f, 0.f};                                            \
    _Pragma("unroll")                                                         \
    for (int n = 0; n < NL; ++n) fin += buf[n] * e[n];                        \
    fin *= scale;                                                             \
    pmax.x = fmaxf(pmax.x, fin.x);                                            \
    pmax.y = fmaxf(pmax.y, fin.y);                                            \
    pmax.z = fmaxf(pmax.z, fin.z);                                            \
    pmax.w = fmaxf(pmax.w, fin.w);                                            \
  } while (0)

  // 2-deep load pipeline; unroll 1 keeps exactly two bodies in scheduling
  // scope (R2's full unroll caused spill catastrophe).
  LOADT(dA, 0);
#pragma unroll 1
  for (int i = 0; i + 2 < TOK_PER_BLK; i += 2) {
    LOADT(dB, i + 1);
    PROCT(dA, i, 0);
    LOADT(dA, i + 2);
    PROCT(dB, i + 1, 1);
  }
  LOADT(dB, TOK_PER_BLK - 1);
  PROCT(dA, TOK_PER_BLK - 2, 0);
  PROCT(dB, TOK_PER_BLK - 1, 1);
#undef LOADT
#undef PROCT

  unsigned* pp = pooled + (size_t)b * H_ + 4 * tid;
  atomicMax(pp + 0, fenc(pmax.x));
  atomicMax(pp + 1, fenc(pmax.y));
  atomicMax(pp + 2, fenc(pmax.z));
  atomicMax(pp + 3, fenc(pmax.w));
}

__global__ __launch_bounds__(256) void logits_kernel(
    const unsigned* __restrict__ pooled, const float* __restrict__ W,
    const float* __restrict__ bias, float* __restrict__ out) {
  const int b = blockIdx.x;
  const int tid = threadIdx.x;
  float a0 = 0.f, a1 = 0.f;
  for (int h = tid; h < H_; h += 256) {
    const float p = fdec(pooled[(size_t)b * H_ + h]);
    a0 += p * W[h];
    a1 += p * W[H_ + h];
  }
#pragma unroll
  for (int off = 32; off >= 1; off >>= 1) {
    a0 += __shfl_xor(a0, off);
    a1 += __shfl_xor(a1, off);
  }
  __shared__ float r0[4], r1[4];
  const int wave = tid >> 6, lane = tid & 63;
  if (lane == 0) { r0[wave] = a0; r1[wave] = a1; }
  __syncthreads();
  if (tid == 0) {
    out[b * 2 + 0] = r0[0] + r0[1] + r0[2] + r0[3] + bias[0];
    out[b * 2 + 1] = r1[0] + r1[1] + r1[2] + r1[3] + bias[1];
  }
}

extern "C" void kernel_launch(void* const* d_in, const int* in_sizes, int n_in,
                              void* d_out, int out_size, void* d_ws, size_t ws_size,
                              hipStream_t stream) {
  const float* hs   = (const float*)d_in[0];
  const float* mask = (const float*)d_in[1];
  const float* W    = (const float*)d_in[2];
  const float* bias = (const float*)d_in[3];
  float* out = (float*)d_out;
  unsigned* pooled = (unsigned*)d_ws;  // B_*H_ u32 = 96 KiB

  hipMemsetAsync(pooled, 0, (size_t)B_ * H_ * sizeof(unsigned), stream);
  hipLaunchKernelGGL(bissect_pool, dim3(B_ * CHUNKS), dim3(THREADS), 0, stream,
                     hs, mask, pooled);
  hipLaunchKernelGGL(logits_kernel, dim3(B_), dim3(256), 0, stream,
                     pooled, W, bias, out);
}

// Round 8
// 102.528 us; speedup vs baseline: 1.6909x; 1.0431x over previous
//
#include <hip/hip_runtime.h>
#include <math.h>

static constexpr int B_ = 32;
static constexpr int T_ = 512;
static constexpr int H_ = 768;
static constexpr int NL = 12;                 // layers 1..12 of 13
static constexpr int CHUNKS = 32;             // blocks per batch item
static constexpr int TOK_PER_BLK = T_ / CHUNKS;   // 16
static constexpr int THREADS = H_ / 4;        // 192 (3 waves)
static constexpr int NW = THREADS / 64;       // 3

typedef float f4 __attribute__((ext_vector_type(4)));

// ---- atomic-path helpers (fallback if ws too small) ----
__device__ __forceinline__ unsigned fenc(float f) {
  unsigned u = __float_as_uint(f);
  return (u & 0x80000000u) ? ~u : (u | 0x80000000u);
}
__device__ __forceinline__ float fdec(unsigned e) {
  return __uint_as_float((e & 0x80000000u) ? (e ^ 0x80000000u) : ~e);
}

// Full wave64 sum via DPP (VALU only, no LDS pipe). Valid in lane 63.
__device__ __forceinline__ float wave64_sum(float x) {
#define DPPADD(ctrl)                                                          \
  x += __int_as_float(__builtin_amdgcn_update_dpp(                            \
      0, __float_as_int(x), (ctrl), 0xf, 0xf, true))
  DPPADD(0x111);  // row_shr:1
  DPPADD(0x112);  // row_shr:2
  DPPADD(0x114);  // row_shr:4
  DPPADD(0x118);  // row_shr:8  -> lanes 15/31/47/63 hold row sums
  DPPADD(0x142);  // row_bcast:15 -> lane31: rows0+1, lane63: rows2+3
  DPPADD(0x143);  // row_bcast:31 -> lane63: full wave sum
#undef DPPADD
  return x;
}

// Shared per-token body. pmax accumulates the per-chunk masked max.
#define BISSECT_BODY                                                          \
  const int tid = threadIdx.x;                                                \
  const int b = blockIdx.x / CHUNKS;                                          \
  const int chunk = blockIdx.x % CHUNKS;                                      \
  const int wave = tid >> 6;                                                  \
  const int lane = tid & 63;                                                  \
  __shared__ float red[2][NW][NL];                                            \
  const size_t layer_stride = (size_t)B_ * T_ * H_;                           \
  const float* tok0 = hs + layer_stride +                                     \
      ((size_t)b * T_ + (size_t)(chunk * TOK_PER_BLK)) * H_ + 4 * tid;        \
  const float* mrow = mask + (size_t)b * T_ + (size_t)(chunk * TOK_PER_BLK);  \
  f4 pmax = {-INFINITY, -INFINITY, -INFINITY, -INFINITY};                     \
  f4 dA[NL], dB[NL];                                                          \
  LOADT(dA, 0);                                                               \
  _Pragma("unroll 1")                                                         \
  for (int i = 0; i + 2 < TOK_PER_BLK; i += 2) {                              \
    LOADT(dB, i + 1);                                                         \
    PROCT(dA, i, 0);                                                          \
    LOADT(dA, i + 2);                                                         \
    PROCT(dB, i + 1, 1);                                                      \
  }                                                                           \
  LOADT(dB, TOK_PER_BLK - 1);                                                 \
  PROCT(dA, TOK_PER_BLK - 2, 0);                                              \
  PROCT(dB, TOK_PER_BLK - 1, 1);

#define LOADT(buf, ti)                                                        \
  do {                                                                        \
    const float* _p = tok0 + (size_t)(ti) * H_;                               \
    _Pragma("unroll")                                                         \
    for (int n = 0; n < NL; ++n)                                              \
      buf[n] = __builtin_nontemporal_load(                                    \
          reinterpret_cast<const f4*>(_p + (size_t)n * layer_stride));        \
  } while (0)

#define PROCT(buf, ti, rb)                                                    \
  do {                                                                        \
    f4 v = buf[0];                                                            \
    _Pragma("unroll")                                                         \
    for (int n = 1; n < NL; ++n) v += buf[n];                                 \
    v *= (1.0f / 12.0f);                                                      \
    float s[NL];                                                              \
    _Pragma("unroll")                                                         \
    for (int n = 0; n < NL; ++n)                                              \
      s[n] = v.x * buf[n].x + v.y * buf[n].y + v.z * buf[n].z + v.w * buf[n].w;\
    _Pragma("unroll")                                                         \
    for (int n = 0; n < NL; ++n) s[n] = wave64_sum(s[n]);                     \
    if (lane == 63) {                                                         \
      _Pragma("unroll")                                                       \
      for (int n = 0; n < NL; ++n) red[rb][wave][n] = s[n];                   \
    }                                                                         \
    __syncthreads();                                                          \
    _Pragma("unroll")                                                         \
    for (int n = 0; n < NL; ++n)                                              \
      s[n] = red[rb][0][n] + red[rb][1][n] + red[rb][2][n];                   \
    float m = s[0];                                                           \
    _Pragma("unroll")                                                         \
    for (int n = 1; n < NL; ++n) m = fmaxf(m, s[n]);                          \
    float e[NL], esum = 0.f;                                                  \
    _Pragma("unroll")                                                         \
    for (int n = 0; n < NL; ++n) { e[n] = __expf(s[n] - m); esum += e[n]; }   \
    const float scale = mrow[ti] / esum;                                      \
    f4 fin = {0.f, 0.f, 0.f, 0.f};                                            \
    _Pragma("unroll")                                                         \
    for (int n = 0; n < NL; ++n) fin += buf[n] * e[n];                        \
    fin *= scale;                                                             \
    pmax.x = fmaxf(pmax.x, fin.x);                                            \
    pmax.y = fmaxf(pmax.y, fin.y);                                            \
    pmax.z = fmaxf(pmax.z, fin.z);                                            \
    pmax.w = fmaxf(pmax.w, fin.w);                                            \
  } while (0)

// ---- primary path: per-chunk partial max, no atomics, no memset ----
__global__ __launch_bounds__(THREADS) void bissect_pool_part(
    const float* __restrict__ hs, const float* __restrict__ mask,
    float* __restrict__ partial) {
  BISSECT_BODY
  // partial[(b*CHUNKS+chunk)*H + 4*tid ..] — plain coalesced store
  float* pp = partial + ((size_t)b * CHUNKS + chunk) * H_ + 4 * tid;
  *reinterpret_cast<f4*>(pp) = pmax;
}

// ---- fallback path: atomicMax on encoded floats (R7 behavior) ----
__global__ __launch_bounds__(THREADS) void bissect_pool_atomic(
    const float* __restrict__ hs, const float* __restrict__ mask,
    unsigned* __restrict__ pooled) {
  BISSECT_BODY
  unsigned* pp = pooled + (size_t)b * H_ + 4 * tid;
  atomicMax(pp + 0, fenc(pmax.x));
  atomicMax(pp + 1, fenc(pmax.y));
  atomicMax(pp + 2, fenc(pmax.z));
  atomicMax(pp + 3, fenc(pmax.w));
}
#undef LOADT
#undef PROCT
#undef BISSECT_BODY

// Fused 32-way max + logits. One block per batch item, 256 threads;
// each thread owns h, h+256, h+512.
__global__ __launch_bounds__(256) void reduce_logits(
    const float* __restrict__ partial, const float* __restrict__ W,
    const float* __restrict__ bias, float* __restrict__ out) {
  const int b = blockIdx.x;
  const int tid = threadIdx.x;
  const float* base = partial + (size_t)b * CHUNKS * H_;
  float m0 = -INFINITY, m1 = -INFINITY, m2 = -INFINITY;
#pragma unroll 4
  for (int c = 0; c < CHUNKS; ++c) {
    const float* row = base + (size_t)c * H_;
    m0 = fmaxf(m0, row[tid]);
    m1 = fmaxf(m1, row[tid + 256]);
    m2 = fmaxf(m2, row[tid + 512]);
  }
  float a0 = m0 * W[tid] + m1 * W[tid + 256] + m2 * W[tid + 512];
  float a1 = m0 * W[H_ + tid] + m1 * W[H_ + tid + 256] + m2 * W[H_ + tid + 512];
#pragma unroll
  for (int off = 32; off >= 1; off >>= 1) {
    a0 += __shfl_xor(a0, off);
    a1 += __shfl_xor(a1, off);
  }
  __shared__ float r0[4], r1[4];
  const int wave = tid >> 6, lane = tid & 63;
  if (lane == 0) { r0[wave] = a0; r1[wave] = a1; }
  __syncthreads();
  if (tid == 0) {
    out[b * 2 + 0] = r0[0] + r0[1] + r0[2] + r0[3] + bias[0];
    out[b * 2 + 1] = r1[0] + r1[1] + r1[2] + r1[3] + bias[1];
  }
}

__global__ __launch_bounds__(256) void logits_kernel(
    const unsigned* __restrict__ pooled, const float* __restrict__ W,
    const float* __restrict__ bias, float* __restrict__ out) {
  const int b = blockIdx.x;
  const int tid = threadIdx.x;
  float a0 = 0.f, a1 = 0.f;
  for (int h = tid; h < H_; h += 256) {
    const float p = fdec(pooled[(size_t)b * H_ + h]);
    a0 += p * W[h];
    a1 += p * W[H_ + h];
  }
#pragma unroll
  for (int off = 32; off >= 1; off >>= 1) {
    a0 += __shfl_xor(a0, off);
    a1 += __shfl_xor(a1, off);
  }
  __shared__ float r0[4], r1[4];
  const int wave = tid >> 6, lane = tid & 63;
  if (lane == 0) { r0[wave] = a0; r1[wave] = a1; }
  __syncthreads();
  if (tid == 0) {
    out[b * 2 + 0] = r0[0] + r0[1] + r0[2] + r0[3] + bias[0];
    out[b * 2 + 1] = r1[0] + r1[1] + r1[2] + r1[3] + bias[1];
  }
}

extern "C" void kernel_launch(void* const* d_in, const int* in_sizes, int n_in,
                              void* d_out, int out_size, void* d_ws, size_t ws_size,
                              hipStream_t stream) {
  const float* hs   = (const float*)d_in[0];
  const float* mask = (const float*)d_in[1];
  const float* W    = (const float*)d_in[2];
  const float* bias = (const float*)d_in[3];
  float* out = (float*)d_out;

  const size_t part_bytes = (size_t)B_ * CHUNKS * H_ * sizeof(float);  // 3 MiB
  if (ws_size >= part_bytes) {
    float* partial = (float*)d_ws;
    hipLaunchKernelGGL(bissect_pool_part, dim3(B_ * CHUNKS), dim3(THREADS), 0,
                       stream, hs, mask, partial);
    hipLaunchKernelGGL(reduce_logits, dim3(B_), dim3(256), 0, stream,
                       partial, W, bias, out);
  } else {
    unsigned* pooled = (unsigned*)d_ws;  // 96 KiB
    hipMemsetAsync(pooled, 0, (size_t)B_ * H_ * sizeof(unsigned), stream);
    hipLaunchKernelGGL(bissect_pool_atomic, dim3(B_ * CHUNKS), dim3(THREADS), 0,
                       stream, hs, mask, pooled);
    hipLaunchKernelGGL(logits_kernel, dim3(B_), dim3(256), 0, stream,
                       pooled, W, bias, out);
  }
}